// Round 2
// baseline (399.307 us; speedup 1.0000x reference)
//
#include <hip/hip_runtime.h>
#include <stdint.h>
#include <stddef.h>

#define NN 50000
#define NE 600000
#define DI 512
#define DH 128
#define DO 40
#define MTOT (NN * DH)   // 6,400,000
#define NBLK ((NN + 255) / 256)   // 196 scan blocks

using int4v = __attribute__((ext_vector_type(4))) int;

// ---------------- threefry2x32 (exact JAX semantics) ----------------
__host__ __device__ inline uint32_t rotl32(uint32_t v, int d) {
  return (v << d) | (v >> (32 - d));
}

__host__ __device__ inline void threefry2x32(uint32_t k0, uint32_t k1,
                                             uint32_t c0, uint32_t c1,
                                             uint32_t* o0, uint32_t* o1) {
  uint32_t ks0 = k0, ks1 = k1, ks2 = k0 ^ k1 ^ 0x1BD11BDAu;
  uint32_t x0 = c0 + ks0, x1 = c1 + ks1;
  const int R0[4] = {13, 15, 26, 6};
  const int R1[4] = {17, 29, 16, 24};
#define TF_R4(R) { x0 += x1; x1 = rotl32(x1, R[0]); x1 ^= x0; \
                   x0 += x1; x1 = rotl32(x1, R[1]); x1 ^= x0; \
                   x0 += x1; x1 = rotl32(x1, R[2]); x1 ^= x0; \
                   x0 += x1; x1 = rotl32(x1, R[3]); x1 ^= x0; }
  TF_R4(R0); x0 += ks1; x1 += ks2 + 1u;
  TF_R4(R1); x0 += ks2; x1 += ks0 + 2u;
  TF_R4(R0); x0 += ks0; x1 += ks1 + 3u;
  TF_R4(R1); x0 += ks1; x1 += ks2 + 4u;
  TF_R4(R0); x0 += ks2; x1 += ks0 + 5u;
#undef TF_R4
  *o0 = x0; *o1 = x1;
}

// ---- BN column sums — EXACT round-7 path (200 blocks x 250 rows) ----------
// NUMERICALLY LIVE: sign(x-mean) ties; do not change grouping or order.
__global__ void colsum_kernel(const float* __restrict__ x,
                              double* __restrict__ colsum) {
  int t = threadIdx.x;               // cols t and t+256
  int r0 = blockIdx.x * 250;
  int r1 = r0 + 250;                 // 200 blocks * 250 = 50000 exactly
  double s0 = 0.0, s1 = 0.0;
  for (int r = r0; r < r1; ++r) {
    s0 += (double)x[(size_t)r * DI + t];
    s1 += (double)x[(size_t)r * DI + t + 256];
  }
  unsafeAtomicAdd(&colsum[t], s0);
  unsafeAtomicAdd(&colsum[t + 256], s1);
}

__global__ void mean_finalize(double* __restrict__ colsum) {
  int c = blockIdx.x * blockDim.x + threadIdx.x;
  if (c < DI) colsum[c] = colsum[c] / (double)NN;
}

// sign(x - mean) -> int8, float4 loads; per-element arithmetic frozen
__global__ void bn_sign(const float* __restrict__ x,
                        const double* __restrict__ mean,
                        int8_t* __restrict__ S0) {
  size_t j4 = (size_t)blockIdx.x * blockDim.x + threadIdx.x;  // 6.4M quads
  const float4 xv = ((const float4*)x)[j4];
  int c = (int)((j4 * 4) & (DI - 1));
  double v0 = (double)xv.x - mean[c];
  double v1 = (double)xv.y - mean[c + 1];
  double v2 = (double)xv.z - mean[c + 2];
  double v3 = (double)xv.w - mean[c + 3];
  uint32_t o = 0;
  o |= (uint8_t)(int8_t)((v0 > 0.0) ? 1 : ((v0 < 0.0) ? -1 : 0));
  o |= ((uint32_t)(uint8_t)(int8_t)((v1 > 0.0) ? 1 : ((v1 < 0.0) ? -1 : 0))) << 8;
  o |= ((uint32_t)(uint8_t)(int8_t)((v2 > 0.0) ? 1 : ((v2 < 0.0) ? -1 : 0))) << 16;
  o |= ((uint32_t)(uint8_t)(int8_t)((v3 > 0.0) ? 1 : ((v3 < 0.0) ? -1 : 0))) << 24;
  ((uint32_t*)S0)[j4] = o;
}

// ---- fused weight prep: MFMA B-fragments straight from float w + sum|w| ----
__global__ void wfuse(const float* __restrict__ w,
                      uint32_t* __restrict__ frag,
                      double* __restrict__ slot,
                      int K, int C, int NT) {
  int steps = K >> 6;
  int total = steps * NT * 64 * 4;
  int idx = blockIdx.x * blockDim.x + threadIdx.x;
  double a = 0.0;
  if (idx < total) {
    int dw = idx & 3;
    int lane = (idx >> 2) & 63;
    int rest = idx >> 8;
    int t = rest % NT;
    int s = rest / NT;
    int n = t * 16 + (lane & 15);
    int kbase = s * 64 + (lane >> 4) * 16 + dw * 4;
    uint32_t v = 0;
    if (n < C) {
#pragma unroll
      for (int j = 0; j < 4; ++j) {
        float wv = w[(size_t)(kbase + j) * C + n];
        uint32_t sg = (uint8_t)(int8_t)((wv > 0.f) ? 1 : ((wv < 0.f) ? -1 : 0));
        v |= sg << (8 * j);
        a += (double)fabsf(wv);
      }
    }
    frag[idx] = v;
  }
  __shared__ double red[256];
  red[threadIdx.x] = a;
  __syncthreads();
  for (int ofs = 128; ofs > 0; ofs >>= 1) {
    if (threadIdx.x < ofs) red[threadIdx.x] += red[threadIdx.x + ofs];
    __syncthreads();
  }
  if (threadIdx.x == 0) unsafeAtomicAdd(slot, red[0]);
}

// ---------------- degree / CSR ----------------
__global__ void deg_edges(const int* __restrict__ ei, uint32_t* __restrict__ deg) {
  int e = blockIdx.x * blockDim.x + threadIdx.x;
  if (e < NE) atomicAdd(&deg[ei[e]], 1u);   // ei[0:E] = destinations
}

__global__ void scan_blocks(const uint32_t* __restrict__ deg,
                            uint32_t* __restrict__ rowptr,
                            uint32_t* __restrict__ bsum,
                            double* __restrict__ dinv) {
  __shared__ uint32_t bs[256];
  int t = threadIdx.x;
  int i = blockIdx.x * 256 + t;
  uint32_t v = (i < NN) ? deg[i] : 0u;
  if (i < NN) dinv[i] = 1.0 / sqrt((double)(v + 1u));   // +1 self-loop
  bs[t] = v;
  __syncthreads();
  for (int ofs = 1; ofs < 256; ofs <<= 1) {
    uint32_t add = (t >= ofs) ? bs[t - ofs] : 0u;
    __syncthreads();
    bs[t] += add;
    __syncthreads();
  }
  if (i < NN) rowptr[i] = bs[t] - v;     // exclusive within block
  if (t == 255) bsum[blockIdx.x] = bs[255];
}

__global__ void scan_bsum(const uint32_t* __restrict__ bsum,
                          uint32_t* __restrict__ base) {
  __shared__ uint32_t bs[256];
  int t = threadIdx.x;
  uint32_t v = (t < NBLK) ? bsum[t] : 0u;
  bs[t] = v;
  __syncthreads();
  for (int ofs = 1; ofs < 256; ofs <<= 1) {
    uint32_t add = (t >= ofs) ? bs[t - ofs] : 0u;
    __syncthreads();
    bs[t] += add;
    __syncthreads();
  }
  if (t < NBLK) base[t] = bs[t] - v;
}

__global__ void scan_addbase(uint32_t* __restrict__ rowptr,
                             const uint32_t* __restrict__ base) {
  int i = blockIdx.x * 256 + threadIdx.x;
  if (i < NN) rowptr[i] += base[blockIdx.x];
  if (i == 0) rowptr[NN] = NE;
}

__global__ void csr_fill(const int* __restrict__ ei,
                         const uint32_t* __restrict__ rowptr,
                         uint32_t* __restrict__ cursor,
                         int* __restrict__ csr_src) {
  int e = blockIdx.x * blockDim.x + threadIdx.x;
  if (e >= NE) return;
  int dst = ei[e], src = ei[NE + e];
  uint32_t pos = rowptr[dst] + atomicAdd(&cursor[dst], 1u);
  csr_src[pos] = src;
}

// ---------------- ternary GEMM via MFMA i8 16x16x64 -----------------------
template <int STEPS, int NT, int C, int SHIFT>
__global__ void gemm_mfma(const int8_t* __restrict__ S,
                          const uint32_t* __restrict__ frag,
                          int8_t* __restrict__ H) {
  extern __shared__ uint4 lb[];
  const int tot = STEPS * NT * 64;
  const uint4* fg = (const uint4*)frag;
  for (int i = threadIdx.x; i < tot; i += 256) lb[i] = fg[i];
  __syncthreads();
  const int lane = threadIdx.x & 63;
  const int wv = threadIdx.x >> 6;
  const int r0 = (blockIdx.x * 4 + wv) * 16;
  if (r0 >= NN) return;                 // NN % 16 == 0
  const int m = lane & 15, q = lane >> 4;
  const int K = STEPS * 64;
  const int8_t* sp = S + (size_t)(r0 + m) * K + q * 16;
  int4v acc[NT];
#pragma unroll
  for (int t = 0; t < NT; ++t) acc[t] = (int4v){0, 0, 0, 0};
#pragma unroll
  for (int s = 0; s < STEPS; ++s) {
    int4v a = *(const int4v*)(sp + (size_t)s * 64);
#pragma unroll
    for (int t = 0; t < NT; ++t) {
      int4v b = *(const int4v*)&lb[(s * NT + t) * 64 + lane];
      acc[t] = __builtin_amdgcn_mfma_i32_16x16x64_i8(a, b, acc[t], 0, 0, 0);
    }
  }
  int8_t* hp = H + (size_t)r0 * C;
#pragma unroll
  for (int t = 0; t < NT; ++t) {
    int n = t * 16 + m;
    if (n < C) {
#pragma unroll
      for (int r = 0; r < 4; ++r)
        hp[(size_t)(q * 4 + r) * C + n] = (int8_t)(acc[t][r] >> SHIFT);
    }
  }
}

// ---- gather (C=128): prefetched, ORDER-PRESERVING vs round 7 --------------
// Two 32-lane groups; group g accumulates edges g, g+2, g+4, ... in strictly
// ascending order (bit-identical f64 sums to round 7). Prefetch: lane l holds
// (src, dinv) for edge l; per-edge values obtained via __shfl executed by ALL
// lanes (tail uses clamped index + w=0 select; +0.0 is sign-inert).
__global__ void gather128(const uint32_t* __restrict__ rowptr,
                          const int* __restrict__ csr_src,
                          const double* __restrict__ dinv,
                          const int8_t* __restrict__ H,
                          const float* __restrict__ b,
                          int8_t* __restrict__ Sout,
                          const double* __restrict__ wsum, double cnt,
                          uint32_t fk0, uint32_t fk1) {
  int d = (int)(((size_t)blockIdx.x * blockDim.x + threadIdx.x) >> 6);
  int lane = threadIdx.x & 63;
  if (d >= NN) return;
  const int g = lane >> 5, p = lane & 31;
  double a0 = 0.0, a1 = 0.0, a2 = 0.0, a3 = 0.0;
  const uint32_t e0 = rowptr[d];
  const int L = (int)(rowptr[d + 1] - e0) + 1;    // + self-loop (edge 0)
  for (int c0 = 0; c0 < L; c0 += 64) {
    const int n = min(64, L - c0);
    const int my = c0 + lane;
    int sidx = d;
    if (my > 0 && my < L) sidx = csr_src[e0 + my - 1];
    double wv = dinv[sidx];                       // sidx=d is valid fallback
    int t = 0;
    for (; t + 4 <= n; t += 4) {                  // jA,jB < n: shfl all-active
      const int jA = t + g, jB = t + 2 + g;
      int sA = __shfl(sidx, jA);  double wA = __shfl(wv, jA);
      int sB = __shfl(sidx, jB);  double wB = __shfl(wv, jB);
      uint32_t hA = *(const uint32_t*)(H + (size_t)sA * DH + 4 * p);
      uint32_t hB = *(const uint32_t*)(H + (size_t)sB * DH + 4 * p);
      a0 += wA * (double)(int8_t)(hA);
      a1 += wA * (double)(int8_t)(hA >> 8);
      a2 += wA * (double)(int8_t)(hA >> 16);
      a3 += wA * (double)(int8_t)(hA >> 24);
      a0 += wB * (double)(int8_t)(hB);
      a1 += wB * (double)(int8_t)(hB >> 8);
      a2 += wB * (double)(int8_t)(hB >> 16);
      a3 += wB * (double)(int8_t)(hB >> 24);
    }
    for (; t < n; t += 2) {                       // non-divergent tail
      const int j = t + g;
      const bool on = (j < n);
      const int jc = on ? j : 0;
      int s = __shfl(sidx, jc);
      double w = __shfl(wv, jc);
      w = on ? w : 0.0;
      uint32_t hv = *(const uint32_t*)(H + (size_t)s * DH + 4 * p);
      a0 += w * (double)(int8_t)(hv);
      a1 += w * (double)(int8_t)(hv >> 8);
      a2 += w * (double)(int8_t)(hv >> 16);
      a3 += w * (double)(int8_t)(hv >> 24);
    }
  }
  a0 += __shfl_xor(a0, 32);
  a1 += __shfl_xor(a1, 32);
  a2 += __shfl_xor(a2, 32);
  a3 += __shfl_xor(a3, 32);
  double sc = (wsum[0] / cnt) * dinv[d];
  int ch = 4 * p + 2 * g;
  int j0 = d * DH + ch;
  double va = sc * ((g == 0) ? a0 : a2) + (double)b[ch];
  double vb = sc * ((g == 0) ? a1 : a3) + (double)b[ch + 1];
  int s0 = (va > 0.0) ? 1 : ((va < 0.0) ? -1 : 0);
  int s1 = (vb > 0.0) ? 1 : ((vb < 0.0) ? -1 : 0);
  uint32_t r0, r1, bits0, bits1;
  threefry2x32(fk0, fk1, 0u, (uint32_t)j0, &r0, &r1);
  bits0 = r0 ^ r1;
  threefry2x32(fk0, fk1, 0u, (uint32_t)(j0 + 1), &r0, &r1);
  bits1 = r0 ^ r1;
  float u0 = __uint_as_float((bits0 >> 9) | 0x3f800000u) - 1.0f;
  float u1 = __uint_as_float((bits1 >> 9) | 0x3f800000u) - 1.0f;
  uint8_t o0 = (u0 < 0.5f) ? (uint8_t)(int8_t)s0 : (uint8_t)0;
  uint8_t o1 = (u1 < 0.5f) ? (uint8_t)(int8_t)s1 : (uint8_t)0;
  *(uint16_t*)(Sout + j0) = (uint16_t)(o0 | ((uint16_t)o1 << 8));
}

// ---- gather (C=40): prefetched, ORDER-PRESERVING vs round 7 ---------------
// Same 2-group structure and channel mapping as round 7 (p<20, 2 ch/lane);
// identical f64 add order -> bit-identical output.
__global__ void gather40_lsm(const uint32_t* __restrict__ rowptr,
                             const int* __restrict__ csr_src,
                             const double* __restrict__ dinv,
                             const int8_t* __restrict__ H,
                             const float* __restrict__ b2,
                             const double* __restrict__ wsum,
                             float* __restrict__ out) {
  int d = (int)(((size_t)blockIdx.x * blockDim.x + threadIdx.x) >> 6);
  int lane = threadIdx.x & 63;
  if (d >= NN) return;
  const int g = lane >> 5, p = lane & 31;
  const bool act = (p < 20);
  double a0 = 0.0, a1 = 0.0;
  const uint32_t e0 = rowptr[d];
  const int L = (int)(rowptr[d + 1] - e0) + 1;
  for (int c0 = 0; c0 < L; c0 += 64) {
    const int n = min(64, L - c0);
    const int my = c0 + lane;
    int sidx = d;
    if (my > 0 && my < L) sidx = csr_src[e0 + my - 1];
    double wv = dinv[sidx];
    int t = 0;
    for (; t + 4 <= n; t += 4) {
      const int jA = t + g, jB = t + 2 + g;
      int sA = __shfl(sidx, jA);  double wA = __shfl(wv, jA);
      int sB = __shfl(sidx, jB);  double wB = __shfl(wv, jB);
      if (act) {
        uint16_t hA = *(const uint16_t*)(H + (size_t)sA * DO + 2 * p);
        uint16_t hB = *(const uint16_t*)(H + (size_t)sB * DO + 2 * p);
        a0 += wA * (double)(int8_t)(hA);
        a1 += wA * (double)(int8_t)(hA >> 8);
        a0 += wB * (double)(int8_t)(hB);
        a1 += wB * (double)(int8_t)(hB >> 8);
      }
    }
    for (; t < n; t += 2) {
      const int j = t + g;
      const bool on = (j < n);
      const int jc = on ? j : 0;
      int s = __shfl(sidx, jc);
      double w = __shfl(wv, jc);
      w = on ? w : 0.0;
      if (act) {
        uint16_t hv = *(const uint16_t*)(H + (size_t)s * DO + 2 * p);
        a0 += w * (double)(int8_t)(hv);
        a1 += w * (double)(int8_t)(hv >> 8);
      }
    }
  }
  a0 += __shfl_xor(a0, 32);
  a1 += __shfl_xor(a1, 32);
  double sc = (wsum[0] / (double)(DH * DO)) * dinv[d];
  const bool lead = (g == 0) && act;
  double v0 = 0.0, v1 = 0.0;
  if (act) {
    v0 = sc * a0 + (double)b2[2 * p];
    v1 = sc * a1 + (double)b2[2 * p + 1];
  }
  double mx = lead ? fmax(v0, v1) : -1.0e300;
  for (int ofs = 32; ofs > 0; ofs >>= 1) mx = fmax(mx, __shfl_xor(mx, ofs));
  float ex = lead ? (expf((float)(v0 - mx)) + expf((float)(v1 - mx))) : 0.f;
  for (int ofs = 32; ofs > 0; ofs >>= 1) ex += __shfl_xor(ex, ofs);
  float l = logf(ex);
  if (lead) {
    float2 o = make_float2((float)(v0 - mx) - l, (float)(v1 - mx) - l);
    *(float2*)(out + (size_t)d * DO + 2 * p) = o;
  }
}

// ---------------- launch ----------------
extern "C" void kernel_launch(void* const* d_in, const int* in_sizes, int n_in,
                              void* d_out, int out_size, void* d_ws, size_t ws_size,
                              hipStream_t stream) {
  (void)in_sizes; (void)n_in; (void)out_size; (void)ws_size;
  const float* x  = (const float*)d_in[0];
  const int*   ei = (const int*)d_in[1];
  const float* w0 = (const float*)d_in[2];
  const float* b0 = (const float*)d_in[3];
  const float* w1 = (const float*)d_in[4];
  const float* b1 = (const float*)d_in[5];
  const float* w2 = (const float*)d_in[6];
  const float* b2 = (const float*)d_in[7];
  float* out = (float*)d_out;

  // ---- workspace carve-up (~42 MB)
  char* wsb = (char*)d_ws;
  double*   mean_d = (double*)wsb;                    // [512] col sums->means
  double*   wsum_d = (double*)(wsb + 4096);           // [3]            pad->4224
  uint32_t* deg_e  = (uint32_t*)(wsb + 4224);         // [NN] edge-only degree
  uint32_t* cursor = (uint32_t*)(wsb + 204224);       // [NN] fill cursors
  // bytes [0, 404224) are zeroed each call
  size_t cur = 404480;
  uint32_t* rowptr = (uint32_t*)(wsb + cur); cur += 200064;   // [NN+1]
  double*   dinv_d = (double*)(wsb + cur);  cur += 400000;
  cur = (cur + 255) & ~255ull;
  uint32_t* bsum = (uint32_t*)(wsb + cur); cur += 1024;       // [NBLK]
  uint32_t* base = (uint32_t*)(wsb + cur); cur += 1024;       // [NBLK]
  int*    csr_src = (int*)(wsb + cur);    cur += (size_t)NE * 4;   // 2.4 MB
  cur = (cur + 255) & ~255ull;
  uint32_t* FR0 = (uint32_t*)(wsb + cur); cur += 8 * 8 * 64 * 16;  // 64 KB
  uint32_t* FR1 = (uint32_t*)(wsb + cur); cur += 2 * 8 * 64 * 16;  // 16 KB
  uint32_t* FR2 = (uint32_t*)(wsb + cur); cur += 2 * 3 * 64 * 16;  // 6 KB
  int8_t* S1  = (int8_t*)(wsb + cur); cur += (size_t)MTOT;         // 6.4 MB
  cur = (cur + 255) & ~255ull;
  int8_t* H8 = (int8_t*)(wsb + cur); cur += (size_t)MTOT;          // 6.4 MB
  cur = (cur + 255) & ~255ull;
  int8_t* S0  = (int8_t*)(wsb + cur);                 // 25.6 MB (dead after gemm0)

  // fold_in(key(42), i): key=(0,42); folded = threefry(key, (0,i)) full output
  uint32_t fkA0, fkA1, fkB0, fkB1;
  threefry2x32(0u, 42u, 0u, 0u, &fkA0, &fkA1);
  threefry2x32(0u, 42u, 0u, 1u, &fkB0, &fkB1);

  // zero mean/wsum/deg/cursor (ws is poisoned 0xAA before every call)
  hipMemsetAsync(wsb, 0, 404224, stream);

  colsum_kernel<<<200, 256, 0, stream>>>(x, mean_d);
  mean_finalize<<<2, 256, 0, stream>>>(mean_d);
  wfuse<<<(8 * 8 * 64 * 4 + 255) / 256, 256, 0, stream>>>(w0, FR0, wsum_d + 0, DI, DH, 8);
  wfuse<<<(2 * 8 * 64 * 4 + 255) / 256, 256, 0, stream>>>(w1, FR1, wsum_d + 1, DH, DH, 8);
  wfuse<<<(2 * 3 * 64 * 4 + 255) / 256, 256, 0, stream>>>(w2, FR2, wsum_d + 2, DH, DO, 3);
  deg_edges<<<(NE + 255) / 256, 256, 0, stream>>>(ei, deg_e);
  scan_blocks<<<NBLK, 256, 0, stream>>>(deg_e, rowptr, bsum, dinv_d);
  scan_bsum<<<1, 256, 0, stream>>>(bsum, base);
  scan_addbase<<<NBLK, 256, 0, stream>>>(rowptr, base);
  csr_fill<<<(NE + 255) / 256, 256, 0, stream>>>(ei, rowptr, cursor, csr_src);
  bn_sign<<<(NN * DI / 4) / 256, 256, 0, stream>>>(x, mean_d, S0);

  const int gemm_blocks = (NN / 16 + 3) / 4;            // 782 (4 waves x 16 rows)
  const int node_blocks = (NN * 64) / 256 + 1;          // 12501 waves >= NN
  const size_t sh0 = 8 * 8 * 64 * 16;                   // 64 KB
  const size_t sh1 = 2 * 8 * 64 * 16;                   // 16 KB
  const size_t sh2 = 2 * 3 * 64 * 16;                   // 6 KB

  // layer 0: K=512 -> DH   (H = h/2 exact; x2 folded into cnt: 65536/2)
  gemm_mfma<8, 8, DH, 1><<<gemm_blocks, 256, sh0, stream>>>(S0, FR0, H8);
  gather128<<<node_blocks, 256, 0, stream>>>(rowptr, csr_src, dinv_d, H8, b0, S1,
                                             wsum_d + 0, (double)(DI * DH / 2),
                                             fkA0, fkA1);

  // layer 1: K=128 -> DH
  gemm_mfma<2, 8, DH, 0><<<gemm_blocks, 256, sh1, stream>>>(S1, FR1, H8);
  gather128<<<node_blocks, 256, 0, stream>>>(rowptr, csr_src, dinv_d, H8, b1, S1,
                                             wsum_d + 1, (double)(DH * DH),
                                             fkB0, fkB1);

  // layer 2: K=128 -> DO, fused log_softmax
  gemm_mfma<2, 3, DO, 0><<<gemm_blocks, 256, sh2, stream>>>(S1, FR2, H8);
  gather40_lsm<<<node_blocks, 256, 0, stream>>>(rowptr, csr_src, dinv_d, H8, b2,
                                                wsum_d + 2, out);
}